// Round 2
// baseline (112.208 us; speedup 1.0000x reference)
//
#include <hip/hip_runtime.h>

#define NLAYER 255
#define SEQ    256
#define TOTJ   32640
#define PG     4            // pass groups; 128 passes total, 32 per group
#define PASSES_PER_GROUP 32
#define THREADS 256

// ---------------------------------------------------------------------------
// Kernel 1: grid (PG, B). Block (g, b) handles row b, passes p in
// [g*32+1, g*32+32]. Pass p >= 2 covers layer p (i = t, t < 256-p) AND layer
// 257-p (i = t-(256-p)) -> exactly 255 lanes busy. Pass 1 covers layer 1
// alone (255 lanes). All LDS reads are stride-1 (conflict-free) or broadcast.
// ---------------------------------------------------------------------------
__global__ __launch_bounds__(THREADS) void main_kernel(
        const float* __restrict__ d1layer,   // B x 255
        const float* __restrict__ hvec,      // B x 32640
        const float* __restrict__ mask,      // B x 255
        float* __restrict__ partials)        // PG*B
{
    __shared__ float c[SEQ];        // c[i] = sum d[0..i-1]
    __shared__ float w[SEQ];        // w[l] = mask[l-1]^2.5 / (256-l), l in [1,255]
    __shared__ float wsum[THREADS / 64];
    __shared__ float red[THREADS / 64];

    const int g = blockIdx.x;
    const int b = blockIdx.y;
    const int t = threadIdx.x;
    const int lane = t & 63;
    const int wid  = t >> 6;

    // ---- stage weights ----
    if (t < NLAYER) {
        float mk = mask[b * NLAYER + t];                 // layer_id = t, layer = t+1
        w[t + 1] = mk * mk * sqrtf(mk) / (float)(NLAYER - t);  // /(256-(t+1))
    }

    // ---- exclusive-ish scan: c[t] = sum d[0..t-1] via wave shuffles ----
    float v = (t > 0) ? d1layer[b * NLAYER + (t - 1)] : 0.0f;
    #pragma unroll
    for (int off = 1; off < 64; off <<= 1) {
        float u = __shfl_up(v, off, 64);
        if (lane >= off) v += u;
    }
    if (lane == 63) wsum[wid] = v;
    __syncthreads();
    float woff = 0.0f;
    #pragma unroll
    for (int i = 0; i < THREADS / 64; ++i)
        if (i < wid) woff += wsum[i];
    c[t] = v + woff;
    __syncthreads();

    // ---- main pass loop ----
    const float* hrow = hvec + (size_t)b * TOTJ;
    const int p0 = g * PASSES_PER_GROUP + 1;

    float acc = 0.0f;
    #pragma unroll 4
    for (int pp = 0; pp < PASSES_PER_GROUP; ++pp) {
        const int p  = p0 + pp;          // wave-uniform
        const int n  = 256 - p;          // elements in layer p
        const int m1 = p - 1;            // layer p segment base
        const int S1 = 256 * m1 - ((m1 * (m1 + 1)) >> 1);
        const int m2 = 256 - p;          // layer (257-p) segment base
        const int S2 = 256 * m2 - ((m2 * (m2 + 1)) >> 1);

        if (t < NLAYER) {                // lane 255 idle (pairs sum to 255)
            const bool first = t < n;
            const int layer = first ? p : (257 - p);
            const int i     = first ? t : (t - n);
            const int hidx  = first ? (S1 + t) : (S2 + t - n);
            float h  = hrow[hidx];
            float dd = (c[i + layer] - c[i]) - h;
            acc += dd * dd * w[layer];
        }
    }

    // ---- block reduction ----
    #pragma unroll
    for (int off = 32; off > 0; off >>= 1)
        acc += __shfl_down(acc, off, 64);
    if (lane == 0) red[wid] = acc;
    __syncthreads();
    if (t == 0) {
        float s = 0.0f;
        #pragma unroll
        for (int i = 0; i < THREADS / 64; ++i) s += red[i];
        partials[b * PG + g] = s;
    }
}

// ---------------------------------------------------------------------------
// Kernel 2: reduce PG*B partials, scale by 1/(255*B), write scalar.
// ---------------------------------------------------------------------------
__global__ __launch_bounds__(256) void reduce_kernel(
        const float* __restrict__ partials, int n, int B,
        float* __restrict__ out)
{
    __shared__ float red[4];
    float acc = 0.0f;
    for (int i = threadIdx.x; i < n; i += 256) acc += partials[i];
    #pragma unroll
    for (int off = 32; off > 0; off >>= 1)
        acc += __shfl_down(acc, off, 64);
    int lane = threadIdx.x & 63, wid = threadIdx.x >> 6;
    if (lane == 0) red[wid] = acc;
    __syncthreads();
    if (threadIdx.x == 0) {
        float s = 0.0f;
        #pragma unroll
        for (int i = 0; i < 4; ++i) s += red[i];
        out[0] = s / ((float)NLAYER * (float)B);
    }
}

// ---------------------------------------------------------------------------
extern "C" void kernel_launch(void* const* d_in, const int* in_sizes, int n_in,
                              void* d_out, int out_size, void* d_ws, size_t ws_size,
                              hipStream_t stream) {
    const float* d1layer = (const float*)d_in[0];   // B x 1 x 255
    const float* hvec    = (const float*)d_in[1];   // B x 32640
    const float* mask    = (const float*)d_in[2];   // B x 255
    float* out = (float*)d_out;

    const int B = in_sizes[2] / NLAYER;             // 512

    float* partials = (float*)d_ws;                 // PG*B floats

    dim3 grid(PG, B);
    main_kernel<<<grid, THREADS, 0, stream>>>(d1layer, hvec, mask, partials);
    reduce_kernel<<<1, 256, 0, stream>>>(partials, PG * B, B, out);
}

// Round 3
// 105.158 us; speedup vs baseline: 1.0670x; 1.0670x over previous
//
#include <hip/hip_runtime.h>

#define NLAYER 255
#define SEQ    256
#define TOTJ   32640
#define CHUNKS 4
#define CHUNK_J (TOTJ / CHUNKS)   // 8160
#define CHUNK_F4 (CHUNK_J / 4)    // 2040
#define THREADS 256

// ---------------------------------------------------------------------------
// Compile-time table: for flat element j (layer l = 1..255, pos i = 0..255-l):
//   bits [0:10)  = layer_id*4           (byte offset into w[])
//   bits [10:21) = (i + (i>>3))*4       (swizzled byte offset of c[i])
//   bits [21:32) = (hi + (hi>>3))*4     (swizzled byte offset of c[i+l])
// Swizzle s(x)=x+(x>>3) turns stride-4 lane access into ~2-way bank aliasing
// (free on gfx950 per m136). Max s(255)=286 -> cs[288] slots.
// ---------------------------------------------------------------------------
struct TblT { unsigned int v[TOTJ]; };
static constexpr TblT make_tbl() {
    TblT t{};
    int idx = 0;
    for (int l = 1; l <= NLAYER; ++l) {
        for (int i = 0; i < 256 - l; ++i) {
            unsigned int lid4 = (unsigned int)((l - 1) * 4);
            unsigned int s0   = (unsigned int)((i + (i >> 3)) * 4);
            int hi = i + l;
            unsigned int s1   = (unsigned int)((hi + (hi >> 3)) * 4);
            t.v[idx++] = lid4 | (s0 << 10) | (s1 << 21);
        }
    }
    return t;
}
__device__ constexpr TblT TBL = make_tbl();

// ---------------------------------------------------------------------------
// Main kernel: grid (CHUNKS, B). Block = (chunk, row).
// ---------------------------------------------------------------------------
__global__ __launch_bounds__(THREADS) void main_kernel(
        const float* __restrict__ d1layer,   // B x 255
        const float* __restrict__ hvec,      // B x 32640
        const float* __restrict__ mask,      // B x 255
        float* __restrict__ partials)        // CHUNKS*B
{
    __shared__ float cs[288];               // swizzled cumsum
    __shared__ float w[NLAYER];             // mask^2.5 / count
    __shared__ float wsum[THREADS / 64];
    __shared__ float red[THREADS / 64];

    const int chunk = blockIdx.x;
    const int b     = blockIdx.y;
    const int t     = threadIdx.x;
    const int lane  = t & 63;
    const int wid   = t >> 6;

    // weights: layer_id = t, count = 255 - t
    if (t < NLAYER) {
        float mk = mask[b * NLAYER + t];
        w[t] = mk * mk * sqrtf(mk) / (float)(NLAYER - t);
    }

    // scan: c[t] = sum d[0..t-1], via wave shuffles + cross-wave fixup
    float v = (t > 0) ? d1layer[b * NLAYER + (t - 1)] : 0.0f;
    #pragma unroll
    for (int off = 1; off < 64; off <<= 1) {
        float u = __shfl_up(v, off, 64);
        if (lane >= off) v += u;
    }
    if (lane == 63) wsum[wid] = v;
    __syncthreads();
    float woff = 0.0f;
    #pragma unroll
    for (int i = 0; i < THREADS / 64; ++i)
        if (i < wid) woff += wsum[i];
    cs[t + (t >> 3)] = v + woff;            // swizzled store
    __syncthreads();

    const float4* hv4 = (const float4*)(hvec + (size_t)b * TOTJ + chunk * CHUNK_J);
    const uint4*  tb4 = (const uint4*)(TBL.v + chunk * CHUNK_J);
    const char* csb = (const char*)cs;
    const char* wb  = (const char*)w;

    float acc = 0.0f;
    #pragma unroll 4
    for (int f4 = t; f4 < CHUNK_F4; f4 += THREADS) {
        float4 h  = hv4[f4];
        uint4  tv = tb4[f4];

        unsigned int e0 = tv.x, e1 = tv.y, e2 = tv.z, e3 = tv.w;

        float d0 = (*(const float*)(csb + (e0 >> 21)) -
                    *(const float*)(csb + ((e0 >> 10) & 0x7FF))) - h.x;
        float d1 = (*(const float*)(csb + (e1 >> 21)) -
                    *(const float*)(csb + ((e1 >> 10) & 0x7FF))) - h.y;
        float d2 = (*(const float*)(csb + (e2 >> 21)) -
                    *(const float*)(csb + ((e2 >> 10) & 0x7FF))) - h.z;
        float d3 = (*(const float*)(csb + (e3 >> 21)) -
                    *(const float*)(csb + ((e3 >> 10) & 0x7FF))) - h.w;

        acc += d0 * d0 * *(const float*)(wb + (e0 & 0x3FF));
        acc += d1 * d1 * *(const float*)(wb + (e1 & 0x3FF));
        acc += d2 * d2 * *(const float*)(wb + (e2 & 0x3FF));
        acc += d3 * d3 * *(const float*)(wb + (e3 & 0x3FF));
    }

    // block reduction
    #pragma unroll
    for (int off = 32; off > 0; off >>= 1)
        acc += __shfl_down(acc, off, 64);
    if (lane == 0) red[wid] = acc;
    __syncthreads();
    if (t == 0) {
        float s = 0.0f;
        #pragma unroll
        for (int i = 0; i < THREADS / 64; ++i) s += red[i];
        partials[b * CHUNKS + chunk] = s;
    }
}

// ---------------------------------------------------------------------------
// Reduce: CHUNKS*B = 2048 partials -> scalar, scaled by 1/(255*B).
// ---------------------------------------------------------------------------
__global__ __launch_bounds__(256) void reduce_kernel(
        const float* __restrict__ partials, int n, int B,
        float* __restrict__ out)
{
    __shared__ float red[4];
    float acc = 0.0f;
    for (int i = threadIdx.x; i < n; i += 256) acc += partials[i];
    #pragma unroll
    for (int off = 32; off > 0; off >>= 1)
        acc += __shfl_down(acc, off, 64);
    int lane = threadIdx.x & 63, wid = threadIdx.x >> 6;
    if (lane == 0) red[wid] = acc;
    __syncthreads();
    if (threadIdx.x == 0) {
        float s = 0.0f;
        #pragma unroll
        for (int i = 0; i < 4; ++i) s += red[i];
        out[0] = s / ((float)NLAYER * (float)B);
    }
}

// ---------------------------------------------------------------------------
extern "C" void kernel_launch(void* const* d_in, const int* in_sizes, int n_in,
                              void* d_out, int out_size, void* d_ws, size_t ws_size,
                              hipStream_t stream) {
    const float* d1layer = (const float*)d_in[0];   // B x 1 x 255
    const float* hvec    = (const float*)d_in[1];   // B x 32640
    const float* mask    = (const float*)d_in[2];   // B x 255
    float* out = (float*)d_out;

    const int B = in_sizes[2] / NLAYER;             // 512

    float* partials = (float*)d_ws;                 // CHUNKS*B floats

    dim3 grid(CHUNKS, B);
    main_kernel<<<grid, THREADS, 0, stream>>>(d1layer, hvec, mask, partials);
    reduce_kernel<<<1, 256, 0, stream>>>(partials, CHUNKS * B, B, out);
}